// Round 7
// baseline (342.576 us; speedup 1.0000x reference)
//
#include <hip/hip_runtime.h>
#include <stdint.h>

#define NN 6144        // nodes
#define NC 576         // padded V columns (517 used)

typedef float f32x4 __attribute__((ext_vector_type(4)));

// f32 -> OCP e4m3fn, RNE, clamp to +-448
__device__ __forceinline__ unsigned char f2e4m3(float f) {
  unsigned u = __float_as_uint(f);
  unsigned sgn = (u >> 24) & 0x80u;
  unsigned au = u & 0x7FFFFFFFu;
  if (au >= 0x43E00000u) return (unsigned char)(sgn | 0x7E);   // >= 448
  if (au < 0x3C800000u) {                                      // < 2^-6: subnormal
    int q = (int)rintf(__uint_as_float(au) * 512.0f);          // step 2^-9
    return (unsigned char)(sgn | (q >= 8 ? 0x08 : q));
  }
  unsigned r = au + 0x7FFFFu + ((au >> 20) & 1u);              // RNE to 3 mantissa bits
  int e = (int)(r >> 23) - 127;
  unsigned m = (r >> 20) & 7u;
  return (unsigned char)(sgn | ((unsigned)(e + 7) << 3) | m);
}

__device__ __forceinline__ void async_load16(const void* g, void* l) {
  __builtin_amdgcn_global_load_lds(
      (__attribute__((address_space(1))) void*)(uintptr_t)g,
      (__attribute__((address_space(3))) void*)(uint32_t)(uintptr_t)l,
      16, 0, 0);
}

// ---------------- Kernel 0: adj int32 -> fp8 (0x00/0x38), MLP-optimized ----------------
// 4608 blocks x 256 thr x 4 groups(8 ints) = 37.7M elems exactly. No LDS; 8 independent
// int4 loads in flight per thread -> ~8 KB/CU outstanding at 32 waves/CU.
__global__ __launch_bounds__(256) void k0_pack(
    const int* __restrict__ adj, unsigned char* __restrict__ A8)
{
  const size_t base = ((size_t)blockIdx.x * 256 + threadIdx.x) * 4;  // uint2-group idx
  const int4* a4 = (const int4*)adj;
  int4 q[8];
#pragma unroll
  for (int i = 0; i < 8; ++i) q[i] = a4[2 * base + i];
  unsigned p[8];
#pragma unroll
  for (int i = 0; i < 8; ++i)
    p[i] = (unsigned)q[i].x * 0x38u | (unsigned)q[i].y * 0x3800u |
           (unsigned)q[i].z * 0x380000u | (unsigned)q[i].w * 0x38000000u;
  uint4* o4 = (uint4*)(A8 + base * 8);
  o4[0] = (uint4){p[0], p[1], p[2], p[3]};
  o4[1] = (uint4){p[4], p[5], p[6], p[7]};
}

// ---------------- Kernel 1: features, score exponentials, V (fp8 col-major), T ----------------
// grid 384 x 256 thr; 16 nodes/block. Thread tile 4 cols x 4 nodes (W traffic halved vs R6;
// xs reads are wave-uniform broadcasts).
__global__ __launch_bounds__(256) void k1_feat(
    const float* __restrict__ x, const float* __restrict__ W,
    const float* __restrict__ Wb, const float* __restrict__ Aw,
    const float* __restrict__ Ab, unsigned char* __restrict__ V8,
    float* __restrict__ e_src, float* __restrict__ T)
{
  __shared__ float xs[256][16];
  __shared__ float hl[16][257];
  __shared__ float sdste[4][16];
  const int t  = threadIdx.x;
  const int nb = blockIdx.x * 16;

  { // stage x
    const int n = t >> 4, kq = (t & 15) * 16;
    const float4* xp = (const float4*)(x + (size_t)(nb + n) * 256 + kq);
#pragma unroll
    for (int j = 0; j < 4; ++j) {
      float4 v = xp[j];
      int k = kq + j * 4;
      xs[k][n] = v.x; xs[k+1][n] = v.y; xs[k+2][n] = v.z; xs[k+3][n] = v.w;
    }
  }
  __syncthreads();

  const int cg = t & 63, ng = t >> 6;      // 4 cols x 4 nodes per thread
  const int c0 = cg * 4, h = c0 >> 6, d0 = c0 & 63;
  const float* wp = W + h * 16384 + d0;    // W[h][k][d], k stride 64
  float acc[4][4];
#pragma unroll
  for (int i = 0; i < 4; ++i)
#pragma unroll
    for (int j = 0; j < 4; ++j) acc[i][j] = 0.f;

#pragma unroll 4
  for (int k = 0; k < 256; ++k) {
    float4 wa = *(const float4*)(wp + (size_t)k * 64);
    float4 xa = *(const float4*)(&xs[k][ng * 4]);   // wave-uniform -> broadcast
    float xr[4] = {xa.x, xa.y, xa.z, xa.w};
    float wr[4] = {wa.x, wa.y, wa.z, wa.w};
#pragma unroll
    for (int i = 0; i < 4; ++i)
#pragma unroll
      for (int j = 0; j < 4; ++j) acc[i][j] += xr[i] * wr[j];
  }
#pragma unroll
  for (int i = 0; i < 4; ++i)
#pragma unroll
    for (int j = 0; j < 4; ++j)
      hl[ng * 4 + i][c0 + j] = acc[i][j] + Wb[c0 + j];
  __syncthreads();

  if (t < 64) { // 16 nodes x 4 heads attention dots
    const int node = t & 15, hd = t >> 4;
    float ss = Ab[hd], sd = 0.f;
#pragma unroll 8
    for (int d = 0; d < 64; ++d) {
      float hv = hl[node][hd * 64 + d];
      ss += hv * Aw[hd * 128 + d];
      sd += hv * Aw[hd * 128 + 64 + d];
    }
    e_src[hd * NN + nb + node] = expf(ss);
    sdste[hd][node] = expf(sd);
  }
  { // T partial (col t)
    float s = 0.f;
#pragma unroll 8
    for (int n2 = 0; n2 < 16; ++n2) s += hl[n2][t];
    atomicAdd(&T[t], s);
  }
  __syncthreads();

  { // write V column-major fp8: 16 groups x 36 cols
    const int n = t & 15, q = t >> 4;
    for (int cc = 0; cc < 36; ++cc) {
      int col = q * 36 + cc;
      float val;
      if (col < 512) {
        int hh = col >> 7, rem = col & 127, d = rem & 63;
        float hv = hl[n][hh * 64 + d];
        val = (rem < 64) ? sdste[hh][n] * hv : hv;
      } else if (col < 516) val = sdste[col - 512][n];
      else if (col == 516)  val = 1.0f;
      else                  val = 0.0f;
      V8[(size_t)col * NN + nb + n] = f2e4m3(val);
    }
  }
}

// ---------------- Kernel 2: out2[ks] = A8 @ V8, A direct-to-VGPR, B async-LDS ----------------
// tile 192x144, BK=64, 4 waves m-stacked (wave tile 48x144, mt3 x nt9).
// grid = ks(nks) x rb(32) x cb(4); nks=6 -> 768 = 3 blocks/CU. LDS 9 KB (B only).
// (unchanged from R6 — verified)
__global__ __launch_bounds__(256, 3) void k2_gemm(
    const unsigned char* __restrict__ A8, const unsigned char* __restrict__ V8,
    float* __restrict__ out2, int nks)
{
  __shared__ unsigned char lB[144 * 64];   // 9,216 B
  const int t   = threadIdx.x;
  const int bid = blockIdx.x;
  const int cb  = bid & 3;
  const int rb  = (bid >> 2) & 31;
  const int ks  = bid >> 7;
  const int krange = NN / nks;
  const int i0 = rb * 192, n0 = cb * 144, k0 = ks * krange;
  const int w = t >> 6, l = t & 63;
  const int lm = l & 15, lk = l >> 4;

  f32x4 acc[3][9];
#pragma unroll
  for (int mt = 0; mt < 3; ++mt)
#pragma unroll
    for (int nt = 0; nt < 9; ++nt) acc[mt][nt] = (f32x4){0.f, 0.f, 0.f, 0.f};

  const unsigned char* gA0 = A8 + (size_t)(i0 + w * 48 + lm) * NN + k0 + lk * 16;

  const int iters = krange / 64;
  for (int it = 0; it < iters; ++it) {
    const int kb = k0 + it * 64;
    { // B staging: 144 cols x 64 B = 576 granules; XOR swizzle (col ^ col>>2)&3
      const unsigned char* gB = V8 + (size_t)n0 * NN + kb;
#pragma unroll
      for (int u = 0; u < 2; ++u) {
        const int gi = u * 256 + t;
        const int col = gi >> 2;
        const int g = (gi & 3) ^ ((col ^ (col >> 2)) & 3);
        async_load16(gB + (size_t)col * NN + g * 16,
                     (char*)lB + (size_t)(u * 256 + (t & ~63)) * 16);
      }
      if (t < 64) {
        const int gi = 512 + t;
        const int col = gi >> 2;
        const int g = (gi & 3) ^ ((col ^ (col >> 2)) & 3);
        async_load16(gB + (size_t)col * NN + g * 16, (char*)lB + (size_t)512 * 16);
      }
    }
    // A direct loads (no LDS): 3 x dwordx4 per thread, covers both ks2 chunks
    longlong2 afr[3];
    const unsigned char* gA = gA0 + it * 64;
#pragma unroll
    for (int mt = 0; mt < 3; ++mt)
      afr[mt] = *(const longlong2*)(gA + (size_t)mt * 16 * NN);
    __syncthreads();   // B ready (drains async loads)
#pragma unroll
    for (int ks2 = 0; ks2 < 2; ++ks2) {
#pragma unroll
      for (int nt = 0; nt < 9; ++nt) {
        const int cc = nt * 16 + lm;
        const int sc = (cc ^ (cc >> 2)) & 3;
        long b = *(const long*)(lB + cc * 64 + ((lk ^ sc) * 16) + ks2 * 8);
#pragma unroll
        for (int mt = 0; mt < 3; ++mt)
          acc[mt][nt] = __builtin_amdgcn_mfma_f32_16x16x32_fp8_fp8(
              ks2 ? afr[mt].y : afr[mt].x, b, acc[mt][nt], 0, 0, 0);
      }
    }
    __syncthreads();
  }

  float* o = out2 + (size_t)ks * ((size_t)NN * NC);
  const int row0 = i0 + w * 48 + lk * 4;
  const int colb = n0 + lm;
#pragma unroll
  for (int mt = 0; mt < 3; ++mt)
#pragma unroll
    for (int nt = 0; nt < 9; ++nt)
#pragma unroll
      for (int rr = 0; rr < 4; ++rr)
        o[(size_t)(row0 + mt * 16 + rr) * NC + colb + nt * 16] = acc[mt][nt][rr];
}

// ---------------- Kernel 3: combine across nks K-partials ----------------
__global__ __launch_bounds__(256) void k3_final(
    const float* __restrict__ out2, const float* __restrict__ e_src,
    const float* __restrict__ T, float* __restrict__ out, int nks)
{
  const int n = blockIdx.x, c = threadIdx.x;
  const int h = c >> 6, d = c & 63;
  float Se = 0.f, Sp = 0.f, E = 0.f, dg = 0.f;
  for (int s = 0; s < nks; ++s) {
    const float* ra = out2 + (size_t)s * ((size_t)NN * NC) + (size_t)n * NC;
    Se += ra[h * 128 + d];
    Sp += ra[h * 128 + 64 + d];
    E  += ra[512 + h];
    dg += ra[516];
  }
  float e = e_src[h * NN + n];
  float D = e * E + ((float)NN - dg);
  out[(size_t)n * 256 + c] = (e * Se + (T[c] - Sp)) / D;
}

extern "C" void kernel_launch(void* const* d_in, const int* in_sizes, int n_in,
                              void* d_out, int out_size, void* d_ws, size_t ws_size,
                              hipStream_t stream) {
  const float* x  = (const float*)d_in[0];
  const int*   adj= (const int*)d_in[1];
  const float* W  = (const float*)d_in[2];
  const float* Wb = (const float*)d_in[3];
  const float* Aw = (const float*)d_in[4];
  const float* Ab = (const float*)d_in[5];
  float* out = (float*)d_out;
  char* ws = (char*)d_ws;
  unsigned char* V8 = (unsigned char*)ws;               // 3,538,944 B
  float* e_src = (float*)(ws + 3538944);                // 98,304 B
  float* T     = (float*)(ws + 3637248);                // 1,024 B
  unsigned char* A8 = (unsigned char*)(ws + 3638272);   // 37,748,736 B
  float* out2  = (float*)(ws + 41387008);               // nks x 14,155,776 B

  const size_t slab = (size_t)NN * NC * 4;
  const size_t base = 41387008;
  int nks = 2;
  if (ws_size >= base + 6 * slab)      nks = 6;   // grid 768 = 3 blocks/CU
  else if (ws_size >= base + 4 * slab) nks = 4;

  hipMemsetAsync(T, 0, 1024, stream);
  hipLaunchKernelGGL(k0_pack, dim3(4608), dim3(256), 0, stream, adj, A8);
  hipLaunchKernelGGL(k1_feat, dim3(384), dim3(256), 0, stream, x, W, Wb, Aw, Ab, V8, e_src, T);
  hipLaunchKernelGGL(k2_gemm, dim3(128 * nks), dim3(256), 0, stream, A8, V8, out2, nks);
  hipLaunchKernelGGL(k3_final, dim3(NN), dim3(256), 0, stream, out2, e_src, T, out, nks);
}

// Round 8
// 329.282 us; speedup vs baseline: 1.0404x; 1.0404x over previous
//
#include <hip/hip_runtime.h>
#include <stdint.h>

#define NN 6144        // nodes
#define NC 576         // padded V columns (517 used)

typedef float f32x4 __attribute__((ext_vector_type(4)));

// f32 -> OCP e4m3fn, RNE, clamp to +-448
__device__ __forceinline__ unsigned char f2e4m3(float f) {
  unsigned u = __float_as_uint(f);
  unsigned sgn = (u >> 24) & 0x80u;
  unsigned au = u & 0x7FFFFFFFu;
  if (au >= 0x43E00000u) return (unsigned char)(sgn | 0x7E);   // >= 448
  if (au < 0x3C800000u) {                                      // < 2^-6: subnormal
    int q = (int)rintf(__uint_as_float(au) * 512.0f);          // step 2^-9
    return (unsigned char)(sgn | (q >= 8 ? 0x08 : q));
  }
  unsigned r = au + 0x7FFFFu + ((au >> 20) & 1u);              // RNE to 3 mantissa bits
  int e = (int)(r >> 23) - 127;
  unsigned m = (r >> 20) & 7u;
  return (unsigned char)(sgn | ((unsigned)(e + 7) << 3) | m);
}

__device__ __forceinline__ void async_load16(const void* g, void* l) {
  __builtin_amdgcn_global_load_lds(
      (__attribute__((address_space(1))) void*)(uintptr_t)g,
      (__attribute__((address_space(3))) void*)(uint32_t)(uintptr_t)l,
      16, 0, 0);
}

// ---------------- Kernel 01: merged feature pass (blocks 0..383) + adj->fp8 pack (384..1919) ----
// Pack part: exact mapping, 12 groups/thread in 3 batches of 4; every instruction
// lane-contiguous (stride 32 B), 8 independent int4 loads in flight per batch.
__global__ __launch_bounds__(256) void k01(
    const float* __restrict__ x, const float* __restrict__ W,
    const float* __restrict__ Wb, const float* __restrict__ Aw,
    const float* __restrict__ Ab, const int* __restrict__ adj,
    unsigned char* __restrict__ V8, unsigned char* __restrict__ A8,
    float* __restrict__ e_src, float* __restrict__ T)
{
  __shared__ float xs[256][16];
  __shared__ float hl[16][257];
  __shared__ float sdste[4][16];
  const int t = threadIdx.x;

  if (blockIdx.x >= 384) {   // ---- pack: adj int32 -> fp8 (0x00 / 0x38) ----
    const int pb = blockIdx.x - 384;             // 0..1535
    const int4* a4 = (const int4*)adj;
    uint2* o2 = (uint2*)A8;
    const unsigned gbase = (unsigned)pb * 3072u + (unsigned)t;
#pragma unroll
    for (int b = 0; b < 3; ++b) {
      int4 q[8];
#pragma unroll
      for (int j = 0; j < 4; ++j) {
        const unsigned g = gbase + (unsigned)(b * 4 + j) * 256u;
        q[2 * j]     = a4[2 * g];
        q[2 * j + 1] = a4[2 * g + 1];
      }
#pragma unroll
      for (int j = 0; j < 4; ++j) {
        const unsigned g = gbase + (unsigned)(b * 4 + j) * 256u;
        uint2 p;
        p.x = (unsigned)q[2*j].x   * 0x38u     | (unsigned)q[2*j].y   * 0x3800u |
              (unsigned)q[2*j].z   * 0x380000u | (unsigned)q[2*j].w   * 0x38000000u;
        p.y = (unsigned)q[2*j+1].x * 0x38u     | (unsigned)q[2*j+1].y * 0x3800u |
              (unsigned)q[2*j+1].z * 0x380000u | (unsigned)q[2*j+1].w * 0x38000000u;
        o2[g] = p;
      }
    }
    return;
  }

  // ---- k1-part: 16 nodes per block (R6-verified structure, 8 cols x 2 nodes) ----
  const int nb = blockIdx.x * 16;
  {
    const int n = t >> 4, kq = (t & 15) * 16;
    const float4* xp = (const float4*)(x + (size_t)(nb + n) * 256 + kq);
#pragma unroll
    for (int j = 0; j < 4; ++j) {
      float4 v = xp[j];
      int k = kq + j * 4;
      xs[k][n] = v.x; xs[k+1][n] = v.y; xs[k+2][n] = v.z; xs[k+3][n] = v.w;
    }
  }
  __syncthreads();

  const int cg = t & 31, ng = t >> 5;
  const int c0 = cg * 8, h = c0 >> 6, d0 = c0 & 63;
  const float* wp = W + h * 16384 + d0;
  float acc[2][8];
#pragma unroll
  for (int i = 0; i < 2; ++i)
#pragma unroll
    for (int j = 0; j < 8; ++j) acc[i][j] = 0.f;

#pragma unroll 4
  for (int k = 0; k < 256; ++k) {
    float4 wa = *(const float4*)(wp + (size_t)k * 64);
    float4 wb = *(const float4*)(wp + (size_t)k * 64 + 4);
    float2 xa = *(const float2*)(&xs[k][ng * 2]);
    float xr[2] = {xa.x, xa.y};
    float wr[8] = {wa.x, wa.y, wa.z, wa.w, wb.x, wb.y, wb.z, wb.w};
#pragma unroll
    for (int i = 0; i < 2; ++i)
#pragma unroll
      for (int j = 0; j < 8; ++j) acc[i][j] += xr[i] * wr[j];
  }
#pragma unroll
  for (int i = 0; i < 2; ++i)
#pragma unroll
    for (int j = 0; j < 8; ++j)
      hl[ng * 2 + i][c0 + j] = acc[i][j] + Wb[c0 + j];
  __syncthreads();

  if (t < 64) {
    const int node = t & 15, hd = t >> 4;
    float ss = Ab[hd], sd = 0.f;
#pragma unroll 8
    for (int d = 0; d < 64; ++d) {
      float hv = hl[node][hd * 64 + d];
      ss += hv * Aw[hd * 128 + d];
      sd += hv * Aw[hd * 128 + 64 + d];
    }
    e_src[hd * NN + nb + node] = expf(ss);
    sdste[hd][node] = expf(sd);
  }
  {
    float s = 0.f;
#pragma unroll 8
    for (int n2 = 0; n2 < 16; ++n2) s += hl[n2][t];
    atomicAdd(&T[t], s);
  }
  __syncthreads();

  { // write V column-major fp8: 16 groups x 36 cols
    const int n = t & 15, q = t >> 4;
    for (int cc = 0; cc < 36; ++cc) {
      int col = q * 36 + cc;
      float val;
      if (col < 512) {
        int hh = col >> 7, rem = col & 127, d = rem & 63;
        float hv = hl[n][hh * 64 + d];
        val = (rem < 64) ? sdste[hh][n] * hv : hv;
      } else if (col < 516) val = sdste[col - 512][n];
      else if (col == 516)  val = 1.0f;
      else                  val = 0.0f;
      V8[(size_t)col * NN + nb + n] = f2e4m3(val);
    }
  }
}

// ---------------- Kernel 2: out2[ks] = A8 @ V8, A direct-to-VGPR, B async-LDS ----------------
// tile 192x144, BK=64, 4 waves m-stacked (wave tile 48x144, mt3 x nt9).
// grid = ks(nks) x rb(32) x cb(4); nks=6 -> 768 = 3 blocks/CU. LDS 9 KB (B only).
// (unchanged from R6/R7 — verified)
__global__ __launch_bounds__(256, 3) void k2_gemm(
    const unsigned char* __restrict__ A8, const unsigned char* __restrict__ V8,
    float* __restrict__ out2, int nks)
{
  __shared__ unsigned char lB[144 * 64];   // 9,216 B
  const int t   = threadIdx.x;
  const int bid = blockIdx.x;
  const int cb  = bid & 3;
  const int rb  = (bid >> 2) & 31;
  const int ks  = bid >> 7;
  const int krange = NN / nks;
  const int i0 = rb * 192, n0 = cb * 144, k0 = ks * krange;
  const int w = t >> 6, l = t & 63;
  const int lm = l & 15, lk = l >> 4;

  f32x4 acc[3][9];
#pragma unroll
  for (int mt = 0; mt < 3; ++mt)
#pragma unroll
    for (int nt = 0; nt < 9; ++nt) acc[mt][nt] = (f32x4){0.f, 0.f, 0.f, 0.f};

  const unsigned char* gA0 = A8 + (size_t)(i0 + w * 48 + lm) * NN + k0 + lk * 16;

  const int iters = krange / 64;
  for (int it = 0; it < iters; ++it) {
    const int kb = k0 + it * 64;
    { // B staging: 144 cols x 64 B = 576 granules; XOR swizzle (col ^ col>>2)&3
      const unsigned char* gB = V8 + (size_t)n0 * NN + kb;
#pragma unroll
      for (int u = 0; u < 2; ++u) {
        const int gi = u * 256 + t;
        const int col = gi >> 2;
        const int g = (gi & 3) ^ ((col ^ (col >> 2)) & 3);
        async_load16(gB + (size_t)col * NN + g * 16,
                     (char*)lB + (size_t)(u * 256 + (t & ~63)) * 16);
      }
      if (t < 64) {
        const int gi = 512 + t;
        const int col = gi >> 2;
        const int g = (gi & 3) ^ ((col ^ (col >> 2)) & 3);
        async_load16(gB + (size_t)col * NN + g * 16, (char*)lB + (size_t)512 * 16);
      }
    }
    // A direct loads (no LDS): 3 x dwordx4 per thread, covers both ks2 chunks
    longlong2 afr[3];
    const unsigned char* gA = gA0 + it * 64;
#pragma unroll
    for (int mt = 0; mt < 3; ++mt)
      afr[mt] = *(const longlong2*)(gA + (size_t)mt * 16 * NN);
    __syncthreads();   // B ready (drains async loads)
#pragma unroll
    for (int ks2 = 0; ks2 < 2; ++ks2) {
#pragma unroll
      for (int nt = 0; nt < 9; ++nt) {
        const int cc = nt * 16 + lm;
        const int sc = (cc ^ (cc >> 2)) & 3;
        long b = *(const long*)(lB + cc * 64 + ((lk ^ sc) * 16) + ks2 * 8);
#pragma unroll
        for (int mt = 0; mt < 3; ++mt)
          acc[mt][nt] = __builtin_amdgcn_mfma_f32_16x16x32_fp8_fp8(
              ks2 ? afr[mt].y : afr[mt].x, b, acc[mt][nt], 0, 0, 0);
      }
    }
    __syncthreads();
  }

  float* o = out2 + (size_t)ks * ((size_t)NN * NC);
  const int row0 = i0 + w * 48 + lk * 4;
  const int colb = n0 + lm;
#pragma unroll
  for (int mt = 0; mt < 3; ++mt)
#pragma unroll
    for (int nt = 0; nt < 9; ++nt)
#pragma unroll
      for (int rr = 0; rr < 4; ++rr)
        o[(size_t)(row0 + mt * 16 + rr) * NC + colb + nt * 16] = acc[mt][nt][rr];
}

// ---------------- Kernel 3: combine across nks K-partials ----------------
__global__ __launch_bounds__(256) void k3_final(
    const float* __restrict__ out2, const float* __restrict__ e_src,
    const float* __restrict__ T, float* __restrict__ out, int nks)
{
  const int n = blockIdx.x, c = threadIdx.x;
  const int h = c >> 6, d = c & 63;
  float Se = 0.f, Sp = 0.f, E = 0.f, dg = 0.f;
  for (int s = 0; s < nks; ++s) {
    const float* ra = out2 + (size_t)s * ((size_t)NN * NC) + (size_t)n * NC;
    Se += ra[h * 128 + d];
    Sp += ra[h * 128 + 64 + d];
    E  += ra[512 + h];
    dg += ra[516];
  }
  float e = e_src[h * NN + n];
  float D = e * E + ((float)NN - dg);
  out[(size_t)n * 256 + c] = (e * Se + (T[c] - Sp)) / D;
}

extern "C" void kernel_launch(void* const* d_in, const int* in_sizes, int n_in,
                              void* d_out, int out_size, void* d_ws, size_t ws_size,
                              hipStream_t stream) {
  const float* x  = (const float*)d_in[0];
  const int*   adj= (const int*)d_in[1];
  const float* W  = (const float*)d_in[2];
  const float* Wb = (const float*)d_in[3];
  const float* Aw = (const float*)d_in[4];
  const float* Ab = (const float*)d_in[5];
  float* out = (float*)d_out;
  char* ws = (char*)d_ws;
  unsigned char* V8 = (unsigned char*)ws;               // 3,538,944 B
  float* e_src = (float*)(ws + 3538944);                // 98,304 B
  float* T     = (float*)(ws + 3637248);                // 1,024 B
  unsigned char* A8 = (unsigned char*)(ws + 3638272);   // 37,748,736 B
  float* out2  = (float*)(ws + 41387008);               // nks x 14,155,776 B

  const size_t slab = (size_t)NN * NC * 4;
  const size_t base = 41387008;
  int nks = 2;
  if (ws_size >= base + 6 * slab)      nks = 6;   // grid 768 = 3 blocks/CU
  else if (ws_size >= base + 4 * slab) nks = 4;

  hipMemsetAsync(T, 0, 1024, stream);
  hipLaunchKernelGGL(k01, dim3(1920), dim3(256), 0, stream,
                     x, W, Wb, Aw, Ab, adj, V8, A8, e_src, T);
  hipLaunchKernelGGL(k2_gemm, dim3(128 * nks), dim3(256), 0, stream, A8, V8, out2, nks);
  hipLaunchKernelGGL(k3_final, dim3(NN), dim3(256), 0, stream, out2, e_src, T, out, nks);
}